// Round 10
// baseline (99.934 us; speedup 1.0000x reference)
//
#include <hip/hip_runtime.h>
#include <stdint.h>

// CorrelationLayer via MFMA Gram tiles.
// out[j*7+i, h, w] = sum_c x[c,h,w] * y[c,h+j-3,w+i-3], zero-padded.
//
// R10: R7's block footprint (1 output row x 64-px slab, LDS y tile
// rows h-3..h+3 (7) x cols ws_blk-4..+67 (72) x k-chunk 32 (pad 40) bf16)
// but 8 waves/block (512 thr) via j-split: wave (ww, kg): ww = 16-px tile,
// kg=0 -> j in {0..3}, kg=1 -> j in {4..6}. Each wave owns complete
// (j, tile) outputs -> no cross-wave accumulation; per-wave slab extraction
// unchanged from R7 (verified). Occupancy: LDS 40320 B -> 3 blocks/CU
// = 24 waves/CU (75%) vs R7's 16 (50%): block phases interleave to hide
// staging latency (R6-R9 lesson: barrier-locked stage->compute with <45%
// occupancy is latency-bound regardless of per-instr cost).
// Staging unit = (row, kb 8k, col-pair): 8 float2 loads -> 8 pkbf ->
// 2 b128 LDS writes; cb even -> pairs never straddle the image edge ->
// single validity mask. 1008 units / 512 thr = 2 phases (2nd masks tid>=496).
// Verified math carried: A/B frag lane {m|n}=l&15, k=(l>>4)*8+e; C/D
// col=lane&15, row=(lane>>4)*4+reg; extraction slab 16x34, i=g / g+4.
// R8 lesson: af[]/acc[] only indexed by compile-time constants.
// Grid 384 h x 8 slabs = 3072; XCD k owns rows [48k,48k+48), slab-fastest.

typedef __attribute__((ext_vector_type(8))) short short8;
typedef __attribute__((ext_vector_type(4))) float floatx4;

constexpr int C = 128;
constexpr int H = 384;
constexpr int W = 512;
constexpr int HW = H * W;

constexpr int NROW = 7;
constexpr int NCOL = 72;              // LDS col 0 = abs ws_blk - 4
constexpr int KP   = 40;              // bf16 per col (32 k + 8 pad) = 80 B
constexpr int ROWB = NCOL * KP * 2;   // 5760 B per row

__device__ __forceinline__ uint32_t pkbf(float a, float b) {
  uint32_t ua = (__float_as_uint(a) + 0x8000u) >> 16;
  uint32_t ub = (__float_as_uint(b) + 0x8000u) & 0xffff0000u;
  return ua | ub;
}

union S8U { uint32_t u[4]; short8 s; };

__device__ __forceinline__ void stage_unit(const float* __restrict__ y,
                                           uint16_t* __restrict__ ys,
                                           int kc, int h, int ws_blk, int u) {
  const int c2  = u % 36;
  const int kb  = (u / 36) & 3;
  const int row = u / 144;                   // 0..6
  const int r_abs = h - 3 + row;
  const int cb    = ws_blk - 4 + 2 * c2;     // even -> no pair straddle
  const bool val = (r_abs >= 0) & (r_abs < H) & (cb >= 0) & (cb <= W - 2);
  const int r  = r_abs < 0 ? 0 : (r_abs >= H ? H - 1 : r_abs);
  const int cc = cb < 0 ? 0 : (cb > W - 2 ? W - 2 : cb);
  const float* src = y + (size_t)(kc * 32 + kb * 8) * HW + (size_t)r * W + cc;
  float2 f[8];
#pragma unroll
  for (int e = 0; e < 8; ++e)
    f[e] = *reinterpret_cast<const float2*>(src + (size_t)e * HW);
  uint4 v0, v1;
  v0.x = pkbf(f[0].x, f[1].x); v0.y = pkbf(f[2].x, f[3].x);
  v0.z = pkbf(f[4].x, f[5].x); v0.w = pkbf(f[6].x, f[7].x);
  v1.x = pkbf(f[0].y, f[1].y); v1.y = pkbf(f[2].y, f[3].y);
  v1.z = pkbf(f[4].y, f[5].y); v1.w = pkbf(f[6].y, f[7].y);
  if (!val) { v0 = make_uint4(0, 0, 0, 0); v1 = make_uint4(0, 0, 0, 0); }
  uint16_t* d0 = &ys[((row * NCOL) + 2 * c2) * KP + kb * 8];
  *reinterpret_cast<uint4*>(d0)      = v0;
  *reinterpret_cast<uint4*>(d0 + KP) = v1;
}

__global__ __launch_bounds__(512, 6)
void corr_mfma(const float* __restrict__ x, const float* __restrict__ y,
               float* __restrict__ out) {
  __shared__ uint16_t ys[NROW * NCOL * KP];   // 40320 B

  const int bid  = blockIdx.x;
  const int idx  = bid >> 3;                  // 0..383
  const int h    = (bid & 7) * 48 + (idx >> 3);
  const int slab = idx & 7;
  const int ws_blk = slab * 64;
  const int tid  = threadIdx.x;
  const int wv   = tid >> 6;
  const int lane = tid & 63;
  const int m  = lane & 15;
  const int g  = lane >> 4;
  const int ww = wv & 3;                      // 16-px tile within slab
  const int kg = wv >> 2;                     // j-split group
  const int ws = ws_blk + ww * 16;
  const int j0 = kg ? 4 : 0;
  const int nj = kg ? 3 : 4;

  floatx4 acc[4][2];
#pragma unroll
  for (int jj = 0; jj < 4; ++jj) {
    acc[jj][0] = (floatx4){0.f, 0.f, 0.f, 0.f};
    acc[jj][1] = (floatx4){0.f, 0.f, 0.f, 0.f};
  }

  // ---- A fragments preload: af[kc], A[m][k] = x[k][h][ws+m], k=g*8+e ----
  short8 af[4];
  {
    const float* xb = x + (size_t)(g * 8) * HW + (size_t)h * W + (ws + m);
#pragma unroll
    for (int kc = 0; kc < 4; ++kc) {
      float f[8];
#pragma unroll
      for (int e = 0; e < 8; ++e) f[e] = xb[(size_t)(kc * 32 + e) * HW];
      S8U s;
      s.u[0] = pkbf(f[0], f[1]);
      s.u[1] = pkbf(f[2], f[3]);
      s.u[2] = pkbf(f[4], f[5]);
      s.u[3] = pkbf(f[6], f[7]);
      af[kc] = s.s;
    }
  }

  // per-lane b128 read byte-offsets within a row slab
  const int col0 = ww * 16 + m + 1;           // abs ws-3+m
  int col1 = col0 + 16;                       // tile1; clamp unused lanes
  if (col1 > NCOL - 1) col1 = NCOL - 1;
  const int fb0 = col0 * (KP * 2) + g * 16;
  const int fb1 = col1 * (KP * 2) + g * 16;

#pragma unroll
  for (int kc = 0; kc < 4; ++kc) {
    if (kc) __syncthreads();                  // protect previous chunk reads
    stage_unit(y, ys, kc, h, ws_blk, tid);
    if (tid < 496) stage_unit(y, ys, kc, h, ws_blk, 512 + tid);
    __syncthreads();

#pragma unroll
    for (int jj = 0; jj < 4; ++jj) {
      if (jj < nj) {                          // wave-uniform guard
        const int j = j0 + jj;
        const uint8_t* rb =
            reinterpret_cast<const uint8_t*>(ys) + j * ROWB;
        const short8 b0 = *reinterpret_cast<const short8*>(rb + fb0);
        const short8 b1 = *reinterpret_cast<const short8*>(rb + fb1);
        acc[jj][0] = __builtin_amdgcn_mfma_f32_16x16x32_bf16(af[kc], b0, acc[jj][0], 0, 0, 0);
        acc[jj][1] = __builtin_amdgcn_mfma_f32_16x16x32_bf16(af[kc], b1, acc[jj][1], 0, 0, 0);
      }
    }
  }

  // ---- extraction: per-wave 16x34 f32 slab (reuses ys after barrier) ----
  __syncthreads();
  float* slabp = reinterpret_cast<float*>(ys) + wv * 544;  // 8*544*4B = 17.4KB
#pragma unroll
  for (int jj = 0; jj < 4; ++jj) {
    if (jj < nj) {                            // wave-uniform guard
      const int j = j0 + jj;
#pragma unroll
      for (int q = 0; q < 4; ++q) {
        slabp[(g * 4 + q) * 34 + m]      = acc[jj][0][q];   // cols 0..15
        slabp[(g * 4 + q) * 34 + 16 + m] = acc[jj][1][q];   // cols 16..31
      }
      const float vo0 = slabp[m * 34 + m + g];              // i = g
      const float vo1 = slabp[m * 34 + m + g + 4];          // i = g+4 (g<3)
      float* ob = out + (size_t)(j * 7 + g) * HW + (size_t)h * W + (ws + m);
      *ob = vo0;
      if (g < 3) ob[(size_t)4 * HW] = vo1;
    }
  }
}

extern "C" void kernel_launch(void* const* d_in, const int* in_sizes, int n_in,
                              void* d_out, int out_size, void* d_ws, size_t ws_size,
                              hipStream_t stream) {
  const float* x = (const float*)d_in[0];
  const float* y = (const float*)d_in[1];
  float* out = (float*)d_out;
  corr_mfma<<<dim3(384 * 8), dim3(512), 0, stream>>>(x, y, out);
}

// Round 11
// 96.988 us; speedup vs baseline: 1.0304x; 1.0304x over previous
//
#include <hip/hip_runtime.h>
#include <stdint.h>

// CorrelationLayer via MFMA Gram tiles — pipelined 2-phase staging.
// out[j*7+i, h, w] = sum_c x[c,h,w] * y[c,h+j-3,w+i-3], zero-padded.
//
// R11: block = 256 thr / 4 waves = (1 h-row x 32-px slab); wave = (ww, kg):
// ww = 16-px tile, kg j-split (kg0: j0..3, kg1: j4..6; acc[4][2]).
// LDS: DOUBLE-buffered y tile [7 rows][40 cols][k32 pad40] bf16 (2x22.4KB).
// One barrier per chunk: issue chunk kc+1's 2-3 staging units' float2 loads
// -> compute chunk kc (ds_read b128 + MFMA) -> pack+ds_write kc+1 -> barrier.
// Load latency hides under compute (T3 minimal 2-phase + T14 issue-early).
// R10 lesson: occupancy tiers make >4 waves/SIMD need <=64 VGPR -> spill;
// stay at the <=128 tier (launch_bounds(256,3), ~116 VGPR).
// Verified math carried: staging decode/clamp/mask = R9/R10; A/B frag lane
// {m|n}=l&15, k=(l>>4)*8+e; C/D col=lane&15,row=(lane>>4)*4+reg; extraction
// slab 16x34 f32, i=g / g+4 (g<3); j-split guard wave-uniform.
// Grid 384 h x 16 slabs = 6144, slab-fastest per XCD; XCD k rows [48k,48k+48)
// (16 blocks share 7 y-rows = 1.8 MB, L2-resident).

typedef __attribute__((ext_vector_type(8))) short short8;
typedef __attribute__((ext_vector_type(4))) float floatx4;

constexpr int C = 128;
constexpr int H = 384;
constexpr int W = 512;
constexpr int HW = H * W;

constexpr int NROW = 7;
constexpr int NCOL = 40;              // LDS col 0 = abs ws_blk - 4
constexpr int KP   = 40;              // bf16 per col (32 k + 8 pad) = 80 B
constexpr int ROWB = NCOL * KP * 2;   // 3200 B per row
constexpr int BUFE = NROW * NCOL * KP;// 11200 bf16 elems per buffer
constexpr int NUNIT = NROW * 4 * (NCOL / 2);  // 560 staging units

__device__ __forceinline__ uint32_t pkbf(float a, float b) {
  uint32_t ua = (__float_as_uint(a) + 0x8000u) >> 16;
  uint32_t ub = (__float_as_uint(b) + 0x8000u) & 0xffff0000u;
  return ua | ub;
}

union S8U { uint32_t u[4]; short8 s; };

// decode staging unit u -> source pointer, validity, LDS element offset
__device__ __forceinline__ void unit_decode(const float* __restrict__ y,
                                            int kc, int h, int ws_blk, int u,
                                            const float*& src, bool& val,
                                            int& ldso) {
  const int c2  = u % 20;
  const int kb  = (u / 20) & 3;
  const int row = u / 80;                    // 0..6
  const int r_abs = h - 3 + row;
  const int cb    = ws_blk - 4 + 2 * c2;     // even -> no pair straddle
  val = (r_abs >= 0) & (r_abs < H) & (cb >= 0) & (cb <= W - 2);
  const int r  = r_abs < 0 ? 0 : (r_abs >= H ? H - 1 : r_abs);
  const int cc = cb < 0 ? 0 : (cb > W - 2 ? W - 2 : cb);
  src  = y + (size_t)(kc * 32 + kb * 8) * HW + (size_t)r * W + cc;
  ldso = (row * NCOL + 2 * c2) * KP + kb * 8;
}

__device__ __forceinline__ void unit_write(uint16_t* __restrict__ buf,
                                           const float2 f[8], bool val,
                                           int ldso) {
  uint4 v0, v1;
  v0.x = pkbf(f[0].x, f[1].x); v0.y = pkbf(f[2].x, f[3].x);
  v0.z = pkbf(f[4].x, f[5].x); v0.w = pkbf(f[6].x, f[7].x);
  v1.x = pkbf(f[0].y, f[1].y); v1.y = pkbf(f[2].y, f[3].y);
  v1.z = pkbf(f[4].y, f[5].y); v1.w = pkbf(f[6].y, f[7].y);
  if (!val) { v0 = make_uint4(0, 0, 0, 0); v1 = make_uint4(0, 0, 0, 0); }
  uint16_t* d0 = &buf[ldso];
  *reinterpret_cast<uint4*>(d0)      = v0;
  *reinterpret_cast<uint4*>(d0 + KP) = v1;
}

__global__ __launch_bounds__(256, 3)
void corr_mfma(const float* __restrict__ x, const float* __restrict__ y,
               float* __restrict__ out) {
  __shared__ uint16_t ys[2][BUFE];           // 44800 B

  const int bid  = blockIdx.x;
  const int idx  = bid >> 3;                 // 0..767
  const int h    = (bid & 7) * 48 + (idx >> 4);
  const int slab = idx & 15;
  const int ws_blk = slab * 32;
  const int tid  = threadIdx.x;
  const int wv   = tid >> 6;
  const int lane = tid & 63;
  const int m  = lane & 15;
  const int g  = lane >> 4;
  const int ww = wv & 1;                     // 16-px tile within slab
  const int kg = wv >> 1;                    // j-split group
  const int ws = ws_blk + ww * 16;
  const int j0 = kg ? 4 : 0;
  const int nj = kg ? 3 : 4;

  floatx4 acc[4][2];
#pragma unroll
  for (int jj = 0; jj < 4; ++jj) {
    acc[jj][0] = (floatx4){0.f, 0.f, 0.f, 0.f};
    acc[jj][1] = (floatx4){0.f, 0.f, 0.f, 0.f};
  }

  // ---- A fragments preload: af[kc], A[m][k] = x[k][h][ws+m], k=g*8+e ----
  short8 af[4];
  {
    const float* xb = x + (size_t)(g * 8) * HW + (size_t)h * W + (ws + m);
#pragma unroll
    for (int kc = 0; kc < 4; ++kc) {
      float f[8];
#pragma unroll
      for (int e = 0; e < 8; ++e) f[e] = xb[(size_t)(kc * 32 + e) * HW];
      S8U s;
      s.u[0] = pkbf(f[0], f[1]);
      s.u[1] = pkbf(f[2], f[3]);
      s.u[2] = pkbf(f[4], f[5]);
      s.u[3] = pkbf(f[6], f[7]);
      af[kc] = s.s;
    }
  }

  // per-lane b128 read byte-offsets within a row slab
  const int col0 = ww * 16 + m + 1;          // abs ws-3+m
  int col1 = col0 + 16;                      // tile1; clamp unused lanes
  if (col1 > NCOL - 1) col1 = NCOL - 1;
  const int fb0 = col0 * (KP * 2) + g * 16;
  const int fb1 = col1 * (KP * 2) + g * 16;

  const bool has2 = (tid < NUNIT - 512);     // threads owning a 3rd unit

  // ---- prologue: stage chunk 0 into ys[0] ----
  {
    const float* s0; const float* s1; const float* s2;
    bool v0, v1, v2; int o0, o1, o2;
    float2 F0[8], F1[8], F2[8];
    unit_decode(y, 0, h, ws_blk, tid,       s0, v0, o0);
    unit_decode(y, 0, h, ws_blk, 256 + tid, s1, v1, o1);
#pragma unroll
    for (int e = 0; e < 8; ++e) {
      F0[e] = *reinterpret_cast<const float2*>(s0 + (size_t)e * HW);
      F1[e] = *reinterpret_cast<const float2*>(s1 + (size_t)e * HW);
    }
    if (has2) {
      unit_decode(y, 0, h, ws_blk, 512 + tid, s2, v2, o2);
#pragma unroll
      for (int e = 0; e < 8; ++e)
        F2[e] = *reinterpret_cast<const float2*>(s2 + (size_t)e * HW);
    }
    unit_write(ys[0], F0, v0, o0);
    unit_write(ys[0], F1, v1, o1);
    if (has2) unit_write(ys[0], F2, v2, o2);
  }
  __syncthreads();

  // ---- main loop: one barrier per chunk, loads issued before compute ----
#pragma unroll
  for (int kc = 0; kc < 4; ++kc) {
    const int cur = kc & 1;
    const int nxt = cur ^ 1;

    // (1) issue chunk kc+1's loads (held in regs across compute)
    const float* s0; const float* s1; const float* s2;
    bool v0 = false, v1 = false, v2 = false; int o0 = 0, o1 = 0, o2 = 0;
    float2 F0[8], F1[8], F2[8];
    if (kc < 3) {
      unit_decode(y, kc + 1, h, ws_blk, tid,       s0, v0, o0);
      unit_decode(y, kc + 1, h, ws_blk, 256 + tid, s1, v1, o1);
#pragma unroll
      for (int e = 0; e < 8; ++e) {
        F0[e] = *reinterpret_cast<const float2*>(s0 + (size_t)e * HW);
        F1[e] = *reinterpret_cast<const float2*>(s1 + (size_t)e * HW);
      }
      if (has2) {
        unit_decode(y, kc + 1, h, ws_blk, 512 + tid, s2, v2, o2);
#pragma unroll
        for (int e = 0; e < 8; ++e)
          F2[e] = *reinterpret_cast<const float2*>(s2 + (size_t)e * HW);
      }
    }

    // (2) compute chunk kc from ys[cur]
#pragma unroll
    for (int jj = 0; jj < 4; ++jj) {
      if (jj < nj) {                         // wave-uniform guard
        const int j = j0 + jj;
        const uint8_t* rb =
            reinterpret_cast<const uint8_t*>(ys[cur]) + j * ROWB;
        const short8 b0 = *reinterpret_cast<const short8*>(rb + fb0);
        const short8 b1 = *reinterpret_cast<const short8*>(rb + fb1);
        acc[jj][0] = __builtin_amdgcn_mfma_f32_16x16x32_bf16(af[kc], b0, acc[jj][0], 0, 0, 0);
        acc[jj][1] = __builtin_amdgcn_mfma_f32_16x16x32_bf16(af[kc], b1, acc[jj][1], 0, 0, 0);
      }
    }

    // (3) pack + write chunk kc+1 into ys[nxt]
    if (kc < 3) {
      unit_write(ys[nxt], F0, v0, o0);
      unit_write(ys[nxt], F1, v1, o1);
      if (has2) unit_write(ys[nxt], F2, v2, o2);
    }
    __syncthreads();
  }

  // ---- extraction: per-wave 16x34 f32 slab (reuses ys[0] after barrier) ----
  float* slabp = reinterpret_cast<float*>(&ys[0][0]) + wv * 544;
#pragma unroll
  for (int jj = 0; jj < 4; ++jj) {
    if (jj < nj) {                           // wave-uniform guard
      const int j = j0 + jj;
#pragma unroll
      for (int q = 0; q < 4; ++q) {
        slabp[(g * 4 + q) * 34 + m]      = acc[jj][0][q];   // cols 0..15
        slabp[(g * 4 + q) * 34 + 16 + m] = acc[jj][1][q];   // cols 16..31
      }
      const float vo0 = slabp[m * 34 + m + g];              // i = g
      const float vo1 = slabp[m * 34 + m + g + 4];          // i = g+4 (g<3)
      float* ob = out + (size_t)(j * 7 + g) * HW + (size_t)h * W + (ws + m);
      *ob = vo0;
      if (g < 3) ob[(size_t)4 * HW] = vo1;
    }
  }
}

extern "C" void kernel_launch(void* const* d_in, const int* in_sizes, int n_in,
                              void* d_out, int out_size, void* d_ws, size_t ws_size,
                              hipStream_t stream) {
  const float* x = (const float*)d_in[0];
  const float* y = (const float*)d_in[1];
  float* out = (float*)d_out;
  corr_mfma<<<dim3(384 * 16), dim3(256), 0, stream>>>(x, y, out);
}

// Round 12
// 77.330 us; speedup vs baseline: 1.2923x; 1.2542x over previous
//
#include <hip/hip_runtime.h>
#include <stdint.h>

// CorrelationLayer via MFMA Gram tiles — 8 output rows/block (halo amortized).
// out[j*7+i, h, w] = sum_c x[c,h,w] * y[c,h+j-3,w+i-3], zero-padded.
//
// R12 theory: R6-R11 all plateaued at 82-100us with every pipe <45% because
// y staging redundancy (7 rows staged per 1 output row) pushed ~1 GB through
// the L2/L3 fabric. Fix: block = 8 output rows x 32-px slab, staging 14 rows
// -> redundancy 7x -> 1.75x, fabric traffic ~1GB -> ~0.3GB.
// Block: 1024 thr / 16 waves; wave (dh 0..7, ww 0..1) owns (h0+dh, 16-px
// tile), all 7 j: acc[7][2] (R7's verified shape). LDS: single 44.8 KB y
// tile [14 rows][40 cols][k32 pad40] bf16, k-contiguous per col (80 B).
// Per chunk: issue kc+1's loads (1 unit/thread: 8 float2) -> compute kc
// (7j x 2 tiles b128+MFMA, B row = dh+j) -> barrier -> write kc+1 -> barrier.
// Staging decode/clamp/mask, A/B frag (lane {m|n}=l&15, k=(l>>4)*8+e),
// C/D (col=lane&15, row=(lane>>4)*4+reg), extraction slab 16x34 (i=g/g+4)
// all byte-identical to passing R7/R9/R11.
// R8/R10 lessons: af[]/acc[] compile-time indexed only; VGPR target <=128
// (launch_bounds(1024,4)); WRITE_SIZE >> 38 MB = spill tell.
// Grid 48 hg x 16 slabs = 768 = 3 x 256 CUs; XCD k owns hg [6k,6k+6).

typedef __attribute__((ext_vector_type(8))) short short8;
typedef __attribute__((ext_vector_type(4))) float floatx4;

constexpr int C = 128;
constexpr int H = 384;
constexpr int W = 512;
constexpr int HW = H * W;

constexpr int NROW = 14;              // rows h0-3 .. h0+10
constexpr int NCOL = 40;              // LDS col 0 = abs ws_blk - 4
constexpr int KP   = 40;              // bf16 per col (32 k + 8 pad) = 80 B
constexpr int ROWB = NCOL * KP * 2;   // 3200 B per row
constexpr int BUFE = NROW * NCOL * KP;          // 22400 bf16 elems (44.8 KB)
constexpr int NUNIT = NROW * 4 * (NCOL / 2);    // 1120 staging units

__device__ __forceinline__ uint32_t pkbf(float a, float b) {
  uint32_t ua = (__float_as_uint(a) + 0x8000u) >> 16;
  uint32_t ub = (__float_as_uint(b) + 0x8000u) & 0xffff0000u;
  return ua | ub;
}

union S8U { uint32_t u[4]; short8 s; };

// decode staging unit u -> source pointer, validity, LDS element offset
__device__ __forceinline__ void unit_decode(const float* __restrict__ y,
                                            int kc, int h0, int ws_blk, int u,
                                            const float*& src, bool& val,
                                            int& ldso) {
  const int c2  = u % 20;
  const int kb  = (u / 20) & 3;
  const int row = u / 80;                    // 0..13
  const int r_abs = h0 - 3 + row;
  const int cb    = ws_blk - 4 + 2 * c2;     // even -> no pair straddle
  val = (r_abs >= 0) & (r_abs < H) & (cb >= 0) & (cb <= W - 2);
  const int r  = r_abs < 0 ? 0 : (r_abs >= H ? H - 1 : r_abs);
  const int cc = cb < 0 ? 0 : (cb > W - 2 ? W - 2 : cb);
  src  = y + (size_t)(kc * 32 + kb * 8) * HW + (size_t)r * W + cc;
  ldso = (row * NCOL + 2 * c2) * KP + kb * 8;
}

__device__ __forceinline__ void unit_write(uint16_t* __restrict__ buf,
                                           const float2 f[8], bool val,
                                           int ldso) {
  uint4 v0, v1;
  v0.x = pkbf(f[0].x, f[1].x); v0.y = pkbf(f[2].x, f[3].x);
  v0.z = pkbf(f[4].x, f[5].x); v0.w = pkbf(f[6].x, f[7].x);
  v1.x = pkbf(f[0].y, f[1].y); v1.y = pkbf(f[2].y, f[3].y);
  v1.z = pkbf(f[4].y, f[5].y); v1.w = pkbf(f[6].y, f[7].y);
  if (!val) { v0 = make_uint4(0, 0, 0, 0); v1 = make_uint4(0, 0, 0, 0); }
  uint16_t* d0 = &buf[ldso];
  *reinterpret_cast<uint4*>(d0)      = v0;
  *reinterpret_cast<uint4*>(d0 + KP) = v1;
}

__global__ __launch_bounds__(1024, 4)
void corr_mfma(const float* __restrict__ x, const float* __restrict__ y,
               float* __restrict__ out) {
  __shared__ uint16_t ys[BUFE];              // 44800 B

  const int bid  = blockIdx.x;
  const int xcd  = bid & 7;
  const int idx  = bid >> 3;                 // 0..95
  const int hg   = xcd * 6 + (idx >> 4);     // 0..47
  const int slab = idx & 15;
  const int h0     = hg * 8;
  const int ws_blk = slab * 32;
  const int tid  = threadIdx.x;
  const int wv   = tid >> 6;                 // 0..15
  const int lane = tid & 63;
  const int m  = lane & 15;
  const int g  = lane >> 4;
  const int dh = wv >> 1;                    // 0..7
  const int ww = wv & 1;                     // 0..1
  const int h  = h0 + dh;
  const int ws = ws_blk + ww * 16;

  const bool has2 = (tid < NUNIT - 1024);    // 96 threads own a 2nd unit

  floatx4 acc[7][2];
#pragma unroll
  for (int j = 0; j < 7; ++j) {
    acc[j][0] = (floatx4){0.f, 0.f, 0.f, 0.f};
    acc[j][1] = (floatx4){0.f, 0.f, 0.f, 0.f};
  }

  // ---- A fragments preload: af[kc], A[m][k] = x[k][h][ws+m], k=g*8+e ----
  short8 af[4];
  {
    const float* xb = x + (size_t)(g * 8) * HW + (size_t)h * W + (ws + m);
#pragma unroll
    for (int kc = 0; kc < 4; ++kc) {
      float f[8];
#pragma unroll
      for (int e = 0; e < 8; ++e) f[e] = xb[(size_t)(kc * 32 + e) * HW];
      S8U s;
      s.u[0] = pkbf(f[0], f[1]);
      s.u[1] = pkbf(f[2], f[3]);
      s.u[2] = pkbf(f[4], f[5]);
      s.u[3] = pkbf(f[6], f[7]);
      af[kc] = s.s;
    }
  }

  // per-lane b128 read byte-offsets within a row slab
  const int col0 = ww * 16 + m + 1;          // abs ws-3+m
  int col1 = col0 + 16;                      // tile1; clamp unused lanes
  if (col1 > NCOL - 1) col1 = NCOL - 1;
  const int fb0 = col0 * (KP * 2) + g * 16;
  const int fb1 = col1 * (KP * 2) + g * 16;

  // ---- prologue: stage chunk 0 ----
  {
    const float* s0; const float* s1;
    bool v0, v1; int o0, o1;
    float2 F0[8], F1[8];
    unit_decode(y, 0, h0, ws_blk, tid, s0, v0, o0);
#pragma unroll
    for (int e = 0; e < 8; ++e)
      F0[e] = *reinterpret_cast<const float2*>(s0 + (size_t)e * HW);
    if (has2) {
      unit_decode(y, 0, h0, ws_blk, 1024 + tid, s1, v1, o1);
#pragma unroll
      for (int e = 0; e < 8; ++e)
        F1[e] = *reinterpret_cast<const float2*>(s1 + (size_t)e * HW);
    }
    unit_write(ys, F0, v0, o0);
    if (has2) unit_write(ys, F1, v1, o1);
  }
  __syncthreads();

  // ---- main loop: issue-early loads, compute, barrier, write-late ----
#pragma unroll
  for (int kc = 0; kc < 4; ++kc) {
    const float* s0; const float* s1;
    bool v0 = false, v1 = false; int o0 = 0, o1 = 0;
    float2 F0[8], F1[8];
    if (kc < 3) {                            // issue chunk kc+1's loads
      unit_decode(y, kc + 1, h0, ws_blk, tid, s0, v0, o0);
#pragma unroll
      for (int e = 0; e < 8; ++e)
        F0[e] = *reinterpret_cast<const float2*>(s0 + (size_t)e * HW);
      if (has2) {
        unit_decode(y, kc + 1, h0, ws_blk, 1024 + tid, s1, v1, o1);
#pragma unroll
        for (int e = 0; e < 8; ++e)
          F1[e] = *reinterpret_cast<const float2*>(s1 + (size_t)e * HW);
      }
    }

    // compute chunk kc: B row = dh + j
#pragma unroll
    for (int j = 0; j < 7; ++j) {
      const uint8_t* rb =
          reinterpret_cast<const uint8_t*>(ys) + (dh + j) * ROWB;
      const short8 b0 = *reinterpret_cast<const short8*>(rb + fb0);
      const short8 b1 = *reinterpret_cast<const short8*>(rb + fb1);
      acc[j][0] = __builtin_amdgcn_mfma_f32_16x16x32_bf16(af[kc], b0, acc[j][0], 0, 0, 0);
      acc[j][1] = __builtin_amdgcn_mfma_f32_16x16x32_bf16(af[kc], b1, acc[j][1], 0, 0, 0);
    }
    __syncthreads();                         // all reads of ys done

    if (kc < 3) {
      unit_write(ys, F0, v0, o0);
      if (has2) unit_write(ys, F1, v1, o1);
      __syncthreads();                       // writes visible before compute
    }
  }

  // ---- extraction: per-wave 16x34 f32 slab (reuses ys; 16*2176B fits) ----
  float* slabp = reinterpret_cast<float*>(ys) + wv * 544;
#pragma unroll
  for (int j = 0; j < 7; ++j) {
#pragma unroll
    for (int q = 0; q < 4; ++q) {
      slabp[(g * 4 + q) * 34 + m]      = acc[j][0][q];   // cols 0..15
      slabp[(g * 4 + q) * 34 + 16 + m] = acc[j][1][q];   // cols 16..31
    }
    const float vo0 = slabp[m * 34 + m + g];             // i = g
    const float vo1 = slabp[m * 34 + m + g + 4];         // i = g+4 (g<3)
    float* ob = out + (size_t)(j * 7 + g) * HW + (size_t)h * W + (ws + m);
    *ob = vo0;
    if (g < 3) ob[(size_t)4 * HW] = vo1;
  }
}

extern "C" void kernel_launch(void* const* d_in, const int* in_sizes, int n_in,
                              void* d_out, int out_size, void* d_ws, size_t ws_size,
                              hipStream_t stream) {
  const float* x = (const float*)d_in[0];
  const float* y = (const float*)d_in[1];
  float* out = (float*)d_out;
  corr_mfma<<<dim3(48 * 16), dim3(1024), 0, stream>>>(x, y, out);
}